// Round 7
// baseline (498.478 us; speedup 1.0000x reference)
//
#include <hip/hip_runtime.h>

#define LSEQ 8192
#define MFFT 16384      // 2*L = 16*16*16*4
#define NT 1024
#define CCH 2048
#define TWO_PI 6.283185307179586f

// XOR bank swizzle: conflict-free for all pass access patterns.
__device__ __forceinline__ int SL(int i) { return i ^ ((i >> 4) & 15); }

__device__ __forceinline__ float2 cmul(float2 a, float2 b) {
    return make_float2(fmaf(a.x, b.x, -a.y * b.y), fmaf(a.x, b.y, a.y * b.x));
}
__device__ __forceinline__ float2 conjf2(float2 a) { return make_float2(a.x, -a.y); }
__device__ __forceinline__ float2 scalef2(float2 a, float s) { return make_float2(a.x * s, a.y * s); }

template<int SGN>
__device__ __forceinline__ void dft4(float2& a0, float2& a1, float2& a2, float2& a3) {
    float t0x = a0.x + a2.x, t0y = a0.y + a2.y;
    float t1x = a0.x - a2.x, t1y = a0.y - a2.y;
    float t2x = a1.x + a3.x, t2y = a1.y + a3.y;
    float t3x = a1.x - a3.x, t3y = a1.y - a3.y;
    float ux = (SGN < 0) ? t3y : -t3y;   // u = SGN*i*t3
    float uy = (SGN < 0) ? -t3x : t3x;
    a0 = make_float2(t0x + t2x, t0y + t2y);
    a1 = make_float2(t1x + ux, t1y + uy);
    a2 = make_float2(t0x - t2x, t0y - t2y);
    a3 = make_float2(t1x - ux, t1y - uy);
}

// Radix-16 DFT over 16 NAMED float2 scalars (prefix P). X[k] ends in
// P{4*(k&3)+(k>>2)} -> SCAT16 below emits in natural-k order.
#define DFT16M(SGN, P) {                                                            \
    dft4<(SGN)>(P##0, P##4, P##8,  P##12);                                          \
    dft4<(SGN)>(P##1, P##5, P##9,  P##13);                                          \
    dft4<(SGN)>(P##2, P##6, P##10, P##14);                                          \
    dft4<(SGN)>(P##3, P##7, P##11, P##15);                                          \
    const float sg_ = (float)(SGN);                                                 \
    const float2 tw1_ = make_float2( 0.9238795325112867f,  sg_ * 0.3826834323650898f); \
    const float2 tw2_ = make_float2( 0.7071067811865476f,  sg_ * 0.7071067811865476f); \
    const float2 tw3_ = make_float2( 0.3826834323650898f,  sg_ * 0.9238795325112867f); \
    const float2 tw6_ = make_float2(-0.7071067811865476f,  sg_ * 0.7071067811865476f); \
    const float2 tw9_ = make_float2(-0.9238795325112867f, -sg_ * 0.3826834323650898f); \
    P##5  = cmul(P##5,  tw1_);                                                      \
    P##6  = cmul(P##6,  tw2_);                                                      \
    P##7  = cmul(P##7,  tw3_);                                                      \
    P##9  = cmul(P##9,  tw2_);                                                      \
    P##10 = make_float2(-sg_ * (P##10).y, sg_ * (P##10).x);                         \
    P##11 = cmul(P##11, tw6_);                                                      \
    P##13 = cmul(P##13, tw3_);                                                      \
    P##14 = cmul(P##14, tw6_);                                                      \
    P##15 = cmul(P##15, tw9_);                                                      \
    dft4<(SGN)>(P##0,  P##1,  P##2,  P##3);                                         \
    dft4<(SGN)>(P##4,  P##5,  P##6,  P##7);                                         \
    dft4<(SGN)>(P##8,  P##9,  P##10, P##11);                                        \
    dft4<(SGN)>(P##12, P##13, P##14, P##15);                                        \
}

// Scatter in natural-k order: k-th output is P{4*(k&3)+(k>>2)}.
#define SCAT16(P, IDXD, NSv)                          \
    ds[SL((IDXD) +  0 * (NSv))] = P##0;               \
    ds[SL((IDXD) +  1 * (NSv))] = P##4;               \
    ds[SL((IDXD) +  2 * (NSv))] = P##8;               \
    ds[SL((IDXD) +  3 * (NSv))] = P##12;              \
    ds[SL((IDXD) +  4 * (NSv))] = P##1;               \
    ds[SL((IDXD) +  5 * (NSv))] = P##5;               \
    ds[SL((IDXD) +  6 * (NSv))] = P##9;               \
    ds[SL((IDXD) +  7 * (NSv))] = P##13;              \
    ds[SL((IDXD) +  8 * (NSv))] = P##2;               \
    ds[SL((IDXD) +  9 * (NSv))] = P##6;               \
    ds[SL((IDXD) + 10 * (NSv))] = P##10;              \
    ds[SL((IDXD) + 11 * (NSv))] = P##14;              \
    ds[SL((IDXD) + 12 * (NSv))] = P##3;               \
    ds[SL((IDXD) + 13 * (NSv))] = P##7;               \
    ds[SL((IDXD) + 14 * (NSv))] = P##11;              \
    ds[SL((IDXD) + 15 * (NSv))] = P##15;

#define LOAD16(P)                                     \
    float2 P##0  = ds[SL(tid)];                       \
    float2 P##1  = ds[SL(tid +  1 * 1024)];           \
    float2 P##2  = ds[SL(tid +  2 * 1024)];           \
    float2 P##3  = ds[SL(tid +  3 * 1024)];           \
    float2 P##4  = ds[SL(tid +  4 * 1024)];           \
    float2 P##5  = ds[SL(tid +  5 * 1024)];           \
    float2 P##6  = ds[SL(tid +  6 * 1024)];           \
    float2 P##7  = ds[SL(tid +  7 * 1024)];           \
    float2 P##8  = ds[SL(tid +  8 * 1024)];           \
    float2 P##9  = ds[SL(tid +  9 * 1024)];           \
    float2 P##10 = ds[SL(tid + 10 * 1024)];           \
    float2 P##11 = ds[SL(tid + 11 * 1024)];           \
    float2 P##12 = ds[SL(tid + 12 * 1024)];           \
    float2 P##13 = ds[SL(tid + 13 * 1024)];           \
    float2 P##14 = ds[SL(tid + 14 * 1024)];           \
    float2 P##15 = ds[SL(tid + 15 * 1024)];

// Per-pass twiddle: P{r} *= wstep^r, wstep = e^{SGN*2pi i/(16*NS) * (tid%NS)}.
#define TWIDDLE15(P, NSv, SGN) {                                              \
    float s1_, c1_;                                                           \
    __sincosf((float)(SGN) * TWO_PI / (float)((NSv) * 16) *                   \
              (float)(tid & ((NSv) - 1)), &s1_, &c1_);                        \
    float2 ws_ = make_float2(c1_, s1_);                                       \
    float2 w_  = ws_;                                                         \
    P##1  = cmul(P##1,  w_);                                                  \
    w_ = cmul(w_, ws_); P##2  = cmul(P##2,  w_);                              \
    w_ = cmul(w_, ws_); P##3  = cmul(P##3,  w_);                              \
    w_ = cmul(w_, ws_); P##4  = cmul(P##4,  w_);                              \
    w_ = cmul(w_, ws_); P##5  = cmul(P##5,  w_);                              \
    w_ = cmul(w_, ws_); P##6  = cmul(P##6,  w_);                              \
    w_ = cmul(w_, ws_); P##7  = cmul(P##7,  w_);                              \
    w_ = cmul(w_, ws_); P##8  = cmul(P##8,  w_);                              \
    w_ = cmul(w_, ws_); P##9  = cmul(P##9,  w_);                              \
    w_ = cmul(w_, ws_); P##10 = cmul(P##10, w_);                              \
    w_ = cmul(w_, ws_); P##11 = cmul(P##11, w_);                              \
    w_ = cmul(w_, ws_); P##12 = cmul(P##12, w_);                              \
    w_ = cmul(w_, ws_); P##13 = cmul(P##13, w_);                              \
    w_ = cmul(w_, ws_); P##14 = cmul(P##14, w_);                              \
    w_ = cmul(w_, ws_); P##15 = cmul(P##15, w_);                              \
}

// Mid Stockham pass (LDS->LDS), NS = 16 or 256.
#define PASS_MID(SGN, NSv) {                                                  \
    LOAD16(m)                                                                 \
    TWIDDLE15(m, NSv, SGN)                                                    \
    DFT16M(SGN, m)                                                            \
    __syncthreads();                                                          \
    const int idxD_ = ((tid & ~((NSv) - 1)) << 4) | (tid & ((NSv) - 1));      \
    SCAT16(m, idxD_, NSv)                                                     \
    __syncthreads();                                                          \
}

// Pairwise spectral multiply for class r: Z[j]=A[j]*K, Z[M-j]=A[M-j]*conj(K).
#define MULT(R, KV) {                                                         \
    const int j_  = tid + ((R) << 10);                                        \
    const int jm_ = MFFT - j_;                                                \
    float2 Aj_ = ds[SL(j_)];                                                  \
    float2 Am_ = ds[SL(jm_)];                                                 \
    float2 Kv_ = (KV);                                                        \
    ds[SL(j_)]  = cmul(Aj_, Kv_);                                             \
    ds[SL(jm_)] = cmul(Am_, conjf2(Kv_));                                     \
}

// Radix-4 final-pass butterfly for one j (loads + twiddle + dft4), scalars by ref.
template<int SGN>
__device__ __forceinline__ void p4b(const float2* ds, int j,
                                    float2& a0, float2& a1, float2& a2, float2& a3) {
    a0 = ds[SL(j)];
    a1 = ds[SL(j + 4096)];
    a2 = ds[SL(j + 8192)];
    a3 = ds[SL(j + 12288)];
    float s1, c1;
    __sincosf((float)SGN * TWO_PI / (float)MFFT * (float)j, &s1, &c1);
    float2 w1 = make_float2(c1, s1);
    float2 w2 = cmul(w1, w1);
    float2 w3 = cmul(w2, w1);
    a1 = cmul(a1, w1);
    a2 = cmul(a2, w2);
    a3 = cmul(a3, w3);
    dft4<SGN>(a0, a1, a2, a3);
}

__global__ __launch_bounds__(NT, 4)   // min 4 waves/EU -> VGPR budget 128
void hyena_fftconv(const float* __restrict__ x,
                   const float* __restrict__ k,
                   const float* __restrict__ bias,
                   float* __restrict__ y)
{
    __shared__ float2 ds[MFFT];          // 128 KiB FFT working buffer
    __shared__ float2 kds[3 * 1024];     // 24 KiB: K bins r=0..2 (class-local)

    const int c   = blockIdx.x;          // one block per channel
    const int tid = threadIdx.x;

    const float* kp  = k + (size_t)c * LSEQ;
    const float* x0p = x + (size_t)c * LSEQ;                // batch 0
    const float* x1p = x + ((size_t)(CCH + c)) * LSEQ;      // batch 1
    float*       y0p = y + (size_t)c * LSEQ;
    float*       y1p = y + ((size_t)(CCH + c)) * LSEQ;
    const float  b0  = bias[c];

    // ================= K = FFT(k)/M  (bias folded into tap s=0) =================
    {
        float2 q0 = make_float2(kp[tid], 0.f);
        if (tid == 0) q0.x += b0;
        float2 q1 = make_float2(kp[tid + 1024], 0.f);
        float2 q2 = make_float2(kp[tid + 2048], 0.f);
        float2 q3 = make_float2(kp[tid + 3072], 0.f);
        float2 q4 = make_float2(kp[tid + 4096], 0.f);
        float2 q5 = make_float2(kp[tid + 5120], 0.f);
        float2 q6 = make_float2(kp[tid + 6144], 0.f);
        float2 q7 = make_float2(kp[tid + 7168], 0.f);
        float2 q8  = make_float2(0.f, 0.f), q9  = make_float2(0.f, 0.f);
        float2 q10 = make_float2(0.f, 0.f), q11 = make_float2(0.f, 0.f);
        float2 q12 = make_float2(0.f, 0.f), q13 = make_float2(0.f, 0.f);
        float2 q14 = make_float2(0.f, 0.f), q15 = make_float2(0.f, 0.f);
        DFT16M(-1, q)
        __syncthreads();
        const int idxD_ = tid << 4;
        SCAT16(q, idxD_, 1)
        __syncthreads();
    }
    PASS_MID(-1, 16)
    PASS_MID(-1, 256)

    // Final radix-4 pass of K-FFT; keep bins {tid + 1024r}: r=0..2 -> kds,
    // r=3..8 -> six named registers. All reads class-local; no barrier needed
    // (next write to ds is behind the x-FFT pass-1 barrier).
    float2 kr3, kr4, kr5, kr6, kr7, kr8;
    {
        const float sc = 1.0f / (float)MFFT;
        float2 a0, a1, a2, a3;
        p4b<-1>(ds, tid, a0, a1, a2, a3);
        kds[tid]        = scalef2(a0, sc);       // r=0
        kr4 = scalef2(a1, sc);                   // r=4
        kr8 = scalef2(a2, sc);                   // r=8 (Nyquist class)
        p4b<-1>(ds, tid + 1024, a0, a1, a2, a3);
        kds[1024 + tid] = scalef2(a0, sc);       // r=1
        kr5 = scalef2(a1, sc);                   // r=5
        p4b<-1>(ds, tid + 2048, a0, a1, a2, a3);
        kds[2048 + tid] = scalef2(a0, sc);       // r=2
        kr6 = scalef2(a1, sc);                   // r=6
        p4b<-1>(ds, tid + 3072, a0, a1, a2, a3);
        kr3 = scalef2(a0, sc);                   // r=3
        kr7 = scalef2(a1, sc);                   // r=7
    }

    // ================= A = FFT(x0 + i*x1) =================
    {
        float2 q0 = make_float2(x0p[tid],        x1p[tid]);
        float2 q1 = make_float2(x0p[tid + 1024], x1p[tid + 1024]);
        float2 q2 = make_float2(x0p[tid + 2048], x1p[tid + 2048]);
        float2 q3 = make_float2(x0p[tid + 3072], x1p[tid + 3072]);
        float2 q4 = make_float2(x0p[tid + 4096], x1p[tid + 4096]);
        float2 q5 = make_float2(x0p[tid + 5120], x1p[tid + 5120]);
        float2 q6 = make_float2(x0p[tid + 6144], x1p[tid + 6144]);
        float2 q7 = make_float2(x0p[tid + 7168], x1p[tid + 7168]);
        float2 q8  = make_float2(0.f, 0.f), q9  = make_float2(0.f, 0.f);
        float2 q10 = make_float2(0.f, 0.f), q11 = make_float2(0.f, 0.f);
        float2 q12 = make_float2(0.f, 0.f), q13 = make_float2(0.f, 0.f);
        float2 q14 = make_float2(0.f, 0.f), q15 = make_float2(0.f, 0.f);
        DFT16M(-1, q)
        __syncthreads();            // all keepK reads of ds complete before overwrite
        const int idxD_ = tid << 4;
        SCAT16(q, idxD_, 1)
        __syncthreads();
    }
    PASS_MID(-1, 16)
    PASS_MID(-1, 256)

    // Final forward radix-4, in place (class-local).
    {
        float2 a0, a1, a2, a3;
        p4b<-1>(ds, tid, a0, a1, a2, a3);
        ds[SL(tid)]         = a0;
        ds[SL(tid + 4096)]  = a1;
        ds[SL(tid + 8192)]  = a2;
        ds[SL(tid + 12288)] = a3;
        p4b<-1>(ds, tid + 1024, a0, a1, a2, a3);
        ds[SL(tid + 1024)]  = a0;
        ds[SL(tid + 5120)]  = a1;
        ds[SL(tid + 9216)]  = a2;
        ds[SL(tid + 13312)] = a3;
        p4b<-1>(ds, tid + 2048, a0, a1, a2, a3);
        ds[SL(tid + 2048)]  = a0;
        ds[SL(tid + 6144)]  = a1;
        ds[SL(tid + 10240)] = a2;
        ds[SL(tid + 14336)] = a3;
        p4b<-1>(ds, tid + 3072, a0, a1, a2, a3);
        ds[SL(tid + 3072)]  = a0;
        ds[SL(tid + 7168)]  = a1;
        ds[SL(tid + 11264)] = a2;
        ds[SL(tid + 15360)] = a3;
    }
    __syncthreads();

    // ===== Z[j]=A[j]K[j], Z[M-j]=A[M-j]conj(K[j])  (K Hermitian) =====
    if (tid == 0) {
        ds[SL(0)]    = cmul(ds[SL(0)],    kds[0]);   // DC (self-paired)
        ds[SL(8192)] = cmul(ds[SL(8192)], kr8);      // Nyquist (self-paired)
    } else {
        const int jm_ = MFFT - tid;
        float2 Aj_ = ds[SL(tid)];
        float2 Am_ = ds[SL(jm_)];
        float2 Kv_ = kds[tid];
        ds[SL(tid)] = cmul(Aj_, Kv_);
        ds[SL(jm_)] = cmul(Am_, conjf2(Kv_));
    }
    MULT(1, kds[1024 + tid])
    MULT(2, kds[2048 + tid])
    MULT(3, kr3)
    MULT(4, kr4)
    MULT(5, kr5)
    MULT(6, kr6)
    MULT(7, kr7)
    __syncthreads();

    // ================= z = IFFT(Z): y0 = Re, y1 = Im =================
    {
        LOAD16(m)
        DFT16M(1, m)
        __syncthreads();
        const int idxD_ = tid << 4;
        SCAT16(m, idxD_, 1)
        __syncthreads();
    }
    PASS_MID(1, 16)
    PASS_MID(1, 256)

    // Final inverse radix-4: only bins < LSEQ stored, straight to HBM.
    {
        float2 a0, a1, a2, a3;
        p4b<1>(ds, tid, a0, a1, a2, a3);
        y0p[tid]        = a0.x;  y1p[tid]        = a0.y;
        y0p[tid + 4096] = a1.x;  y1p[tid + 4096] = a1.y;
        p4b<1>(ds, tid + 1024, a0, a1, a2, a3);
        y0p[tid + 1024] = a0.x;  y1p[tid + 1024] = a0.y;
        y0p[tid + 5120] = a1.x;  y1p[tid + 5120] = a1.y;
        p4b<1>(ds, tid + 2048, a0, a1, a2, a3);
        y0p[tid + 2048] = a0.x;  y1p[tid + 2048] = a0.y;
        y0p[tid + 6144] = a1.x;  y1p[tid + 6144] = a1.y;
        p4b<1>(ds, tid + 3072, a0, a1, a2, a3);
        y0p[tid + 3072] = a0.x;  y1p[tid + 3072] = a0.y;
        y0p[tid + 7168] = a1.x;  y1p[tid + 7168] = a1.y;
    }
}

extern "C" void kernel_launch(void* const* d_in, const int* in_sizes, int n_in,
                              void* d_out, int out_size, void* d_ws, size_t ws_size,
                              hipStream_t stream) {
    const float* x    = (const float*)d_in[0];
    const float* k    = (const float*)d_in[1];
    const float* bias = (const float*)d_in[2];
    float* y          = (float*)d_out;

    hyena_fftconv<<<dim3(CCH), dim3(NT), 0, stream>>>(x, k, bias, y);
}

// Round 8
// 273.195 us; speedup vs baseline: 1.8246x; 1.8246x over previous
//
#include <hip/hip_runtime.h>

#define LSEQ 8192
#define MFFT 16384      // 2*L = 8*8*8*8*4
#define NT 1024
#define CCH 2048
#define TWO_PI 6.283185307179586f
#define KSTRIDE 8208    // float2 stride per channel in workspace (>=8193, mult of 16)

// XOR bank swizzle: conflict-free (or free 2-way) for all pass access patterns.
__device__ __forceinline__ int SL(int i) { return i ^ ((i >> 4) & 15); }

__device__ __forceinline__ float2 cmul(float2 a, float2 b) {
    return make_float2(fmaf(a.x, b.x, -a.y * b.y), fmaf(a.x, b.y, a.y * b.x));
}
__device__ __forceinline__ float2 conjf2(float2 a) { return make_float2(a.x, -a.y); }
__device__ __forceinline__ float2 scalef2(float2 a, float s) { return make_float2(a.x * s, a.y * s); }

template<int SGN>
__device__ __forceinline__ void dft4(float2& a0, float2& a1, float2& a2, float2& a3) {
    float t0x = a0.x + a2.x, t0y = a0.y + a2.y;
    float t1x = a0.x - a2.x, t1y = a0.y - a2.y;
    float t2x = a1.x + a3.x, t2y = a1.y + a3.y;
    float t3x = a1.x - a3.x, t3y = a1.y - a3.y;
    float ux = (SGN < 0) ? t3y : -t3y;   // u = SGN*i*t3
    float uy = (SGN < 0) ? -t3x : t3x;
    a0 = make_float2(t0x + t2x, t0y + t2y);
    a1 = make_float2(t1x + ux, t1y + uy);
    a2 = make_float2(t0x - t2x, t0y - t2y);
    a3 = make_float2(t1x - ux, t1y - uy);
}

// Natural-order 8-point DFT (DIT: evens/odds dft4 + W8 combine).
template<int SGN>
__device__ __forceinline__ void dft8(float2& v0, float2& v1, float2& v2, float2& v3,
                                     float2& v4, float2& v5, float2& v6, float2& v7) {
    float2 e0 = v0, e1 = v2, e2 = v4, e3 = v6;
    float2 o0 = v1, o1 = v3, o2 = v5, o3 = v7;
    dft4<SGN>(e0, e1, e2, e3);
    dft4<SGN>(o0, o1, o2, o3);
    const float sg = (float)SGN;
    const float H = 0.7071067811865476f;
    float2 t1 = cmul(o1, make_float2( H, sg * H));
    float2 t2 = make_float2(-sg * o2.y, sg * o2.x);        // o2 * W8^2
    float2 t3 = cmul(o3, make_float2(-H, sg * H));
    v0 = make_float2(e0.x + o0.x, e0.y + o0.y);
    v4 = make_float2(e0.x - o0.x, e0.y - o0.y);
    v1 = make_float2(e1.x + t1.x, e1.y + t1.y);
    v5 = make_float2(e1.x - t1.x, e1.y - t1.y);
    v2 = make_float2(e2.x + t2.x, e2.y + t2.y);
    v6 = make_float2(e2.x - t2.x, e2.y - t2.y);
    v3 = make_float2(e3.x + t3.x, e3.y + t3.y);
    v7 = make_float2(e3.x - t3.x, e3.y - t3.y);
}

// Radix-8 Stockham reads: always stride N/8 = 2048.
#define RD8(P, B)                              \
    float2 P##0 = ds[SL(B)];                   \
    float2 P##1 = ds[SL((B) + 2048)];          \
    float2 P##2 = ds[SL((B) + 4096)];          \
    float2 P##3 = ds[SL((B) + 6144)];          \
    float2 P##4 = ds[SL((B) + 8192)];          \
    float2 P##5 = ds[SL((B) + 10240)];         \
    float2 P##6 = ds[SL((B) + 12288)];         \
    float2 P##7 = ds[SL((B) + 14336)];

// Twiddle P{r} *= w^r, w = e^{SGN*2pi i/(8*NS) * (B mod NS)}.
#define TW8(P, B, NSv, SGN) {                                                 \
    float s_, c_;                                                             \
    __sincosf((float)(SGN) * TWO_PI / (float)((NSv) * 8) *                    \
              (float)((B) & ((NSv) - 1)), &s_, &c_);                          \
    const float2 w1_ = make_float2(c_, s_);                                   \
    float2 wc_ = w1_;                                                         \
    P##1 = cmul(P##1, wc_);                                                   \
    wc_ = cmul(wc_, w1_); P##2 = cmul(P##2, wc_);                             \
    wc_ = cmul(wc_, w1_); P##3 = cmul(P##3, wc_);                             \
    wc_ = cmul(wc_, w1_); P##4 = cmul(P##4, wc_);                             \
    wc_ = cmul(wc_, w1_); P##5 = cmul(P##5, wc_);                             \
    wc_ = cmul(wc_, w1_); P##6 = cmul(P##6, wc_);                             \
    wc_ = cmul(wc_, w1_); P##7 = cmul(P##7, wc_);                             \
}

// Stockham writes: dest = (B/NS)*8NS + (B mod NS) + NS*r.
#define WR8(P, B, NSv) {                                                      \
    const int i_ = (B) & ((NSv) - 1);                                         \
    const int d_ = (((B) - i_) << 3) + i_;                                    \
    ds[SL(d_)]                = P##0;                                         \
    ds[SL(d_ +     (NSv))]    = P##1;                                         \
    ds[SL(d_ + 2 * (NSv))]    = P##2;                                         \
    ds[SL(d_ + 3 * (NSv))]    = P##3;                                         \
    ds[SL(d_ + 4 * (NSv))]    = P##4;                                         \
    ds[SL(d_ + 5 * (NSv))]    = P##5;                                         \
    ds[SL(d_ + 6 * (NSv))]    = P##6;                                         \
    ds[SL(d_ + 7 * (NSv))]    = P##7;                                         \
}

#define DFT8C(SGN, P) dft8<(SGN)>(P##0, P##1, P##2, P##3, P##4, P##5, P##6, P##7);

// Mid radix-8 pass (LDS->LDS), two butterflies/thread, NS in {8,64,512}.
#define P8PASS(SGN, NSv) {                                                    \
    RD8(pa, tid)                                                              \
    TW8(pa, tid, NSv, SGN)                                                    \
    DFT8C(SGN, pa)                                                            \
    RD8(pb, tid + 1024)                                                       \
    TW8(pb, tid + 1024, NSv, SGN)                                             \
    DFT8C(SGN, pb)                                                            \
    __syncthreads();                                                          \
    WR8(pa, tid, NSv)                                                         \
    WR8(pb, tid + 1024, NSv)                                                  \
    __syncthreads();                                                          \
}

// First pass (NS=1, no twiddle) reading from LDS (used by inverse FFT).
#define P8FIRST_LDS(SGN) {                                                    \
    RD8(pa, tid)                                                              \
    DFT8C(SGN, pa)                                                            \
    RD8(pb, tid + 1024)                                                       \
    DFT8C(SGN, pb)                                                            \
    __syncthreads();                                                          \
    WR8(pa, tid, 1)                                                           \
    WR8(pb, tid + 1024, 1)                                                    \
    __syncthreads();                                                          \
}

// Final radix-4 pass butterfly (NS=4096): loads + twiddle + dft4.
template<int SGN>
__device__ __forceinline__ void p4b(const float2* ds, int j,
                                    float2& a0, float2& a1, float2& a2, float2& a3) {
    a0 = ds[SL(j)];
    a1 = ds[SL(j + 4096)];
    a2 = ds[SL(j + 8192)];
    a3 = ds[SL(j + 12288)];
    float s1, c1;
    __sincosf((float)SGN * TWO_PI / (float)MFFT * (float)j, &s1, &c1);
    float2 w1 = make_float2(c1, s1);
    float2 w2 = cmul(w1, w1);
    float2 w3 = cmul(w2, w1);
    a1 = cmul(a1, w1);
    a2 = cmul(a2, w2);
    a3 = cmul(a3, w3);
    dft4<SGN>(a0, a1, a2, a3);
}

// ===================== Kernel A: K spectrum -> workspace =====================
__global__ __launch_bounds__(NT)
void hyena_kfft(const float* __restrict__ k, const float* __restrict__ bias,
                float2* __restrict__ kw)
{
    __shared__ float2 ds[MFFT];
    const int c = blockIdx.x, tid = threadIdx.x;
    const float* kp = k + (size_t)c * LSEQ;
    const float b0 = bias[c];

    // pass0 (radix-8, NS=1): load from global, top half zero (zero-padding).
    {
        float2 pa0 = make_float2(kp[tid], 0.f);
        if (tid == 0) pa0.x += b0;                    // bias = conv tap s=0
        float2 pa1 = make_float2(kp[tid + 2048], 0.f);
        float2 pa2 = make_float2(kp[tid + 4096], 0.f);
        float2 pa3 = make_float2(kp[tid + 6144], 0.f);
        float2 pa4 = make_float2(0.f, 0.f), pa5 = make_float2(0.f, 0.f);
        float2 pa6 = make_float2(0.f, 0.f), pa7 = make_float2(0.f, 0.f);
        DFT8C(-1, pa)
        float2 pb0 = make_float2(kp[tid + 1024], 0.f);
        float2 pb1 = make_float2(kp[tid + 3072], 0.f);
        float2 pb2 = make_float2(kp[tid + 5120], 0.f);
        float2 pb3 = make_float2(kp[tid + 7168], 0.f);
        float2 pb4 = make_float2(0.f, 0.f), pb5 = make_float2(0.f, 0.f);
        float2 pb6 = make_float2(0.f, 0.f), pb7 = make_float2(0.f, 0.f);
        DFT8C(-1, pb)
        WR8(pa, tid, 1)
        WR8(pb, tid + 1024, 1)
        __syncthreads();
    }
    P8PASS(-1, 8)
    P8PASS(-1, 64)
    P8PASS(-1, 512)

    // final radix-4: bins class-local; write Hermitian half (0..8192) scaled.
    {
        const float sc = 1.0f / (float)MFFT;
        float2* kc = kw + (size_t)c * KSTRIDE;
        float2 a0, a1, a2, a3;
        p4b<-1>(ds, tid, a0, a1, a2, a3);
        kc[tid]        = scalef2(a0, sc);
        kc[tid + 4096] = scalef2(a1, sc);
        if (tid == 0) kc[8192] = scalef2(a2, sc);     // Nyquist
        p4b<-1>(ds, tid + 1024, a0, a1, a2, a3);
        kc[tid + 1024] = scalef2(a0, sc);
        kc[tid + 5120] = scalef2(a1, sc);
        p4b<-1>(ds, tid + 2048, a0, a1, a2, a3);
        kc[tid + 2048] = scalef2(a0, sc);
        kc[tid + 6144] = scalef2(a1, sc);
        p4b<-1>(ds, tid + 3072, a0, a1, a2, a3);
        kc[tid + 3072] = scalef2(a0, sc);
        kc[tid + 7168] = scalef2(a1, sc);
    }
}

// ============ Kernel B: A=FFT(x0+i*x1), Z=A*K, y0=Re(IFFT), y1=Im ============
__global__ __launch_bounds__(NT)
void hyena_xconv(const float* __restrict__ x, const float2* __restrict__ kw,
                 float* __restrict__ y)
{
    __shared__ float2 ds[MFFT];
    const int c = blockIdx.x, tid = threadIdx.x;
    const float* x0p = x + (size_t)c * LSEQ;
    const float* x1p = x + ((size_t)(CCH + c)) * LSEQ;
    float*       y0p = y + (size_t)c * LSEQ;
    float*       y1p = y + ((size_t)(CCH + c)) * LSEQ;

    // forward pass0 (radix-8, NS=1) straight from global.
    {
        float2 pa0 = make_float2(x0p[tid],        x1p[tid]);
        float2 pa1 = make_float2(x0p[tid + 2048], x1p[tid + 2048]);
        float2 pa2 = make_float2(x0p[tid + 4096], x1p[tid + 4096]);
        float2 pa3 = make_float2(x0p[tid + 6144], x1p[tid + 6144]);
        float2 pa4 = make_float2(0.f, 0.f), pa5 = make_float2(0.f, 0.f);
        float2 pa6 = make_float2(0.f, 0.f), pa7 = make_float2(0.f, 0.f);
        DFT8C(-1, pa)
        float2 pb0 = make_float2(x0p[tid + 1024], x1p[tid + 1024]);
        float2 pb1 = make_float2(x0p[tid + 3072], x1p[tid + 3072]);
        float2 pb2 = make_float2(x0p[tid + 5120], x1p[tid + 5120]);
        float2 pb3 = make_float2(x0p[tid + 7168], x1p[tid + 7168]);
        float2 pb4 = make_float2(0.f, 0.f), pb5 = make_float2(0.f, 0.f);
        float2 pb6 = make_float2(0.f, 0.f), pb7 = make_float2(0.f, 0.f);
        DFT8C(-1, pb)
        WR8(pa, tid, 1)
        WR8(pb, tid + 1024, 1)
        __syncthreads();
    }
    P8PASS(-1, 8)
    P8PASS(-1, 64)
    P8PASS(-1, 512)
    // final forward radix-4 in place (class-local).
    {
        float2 a0, a1, a2, a3;
        p4b<-1>(ds, tid, a0, a1, a2, a3);
        ds[SL(tid)]         = a0;  ds[SL(tid + 4096)]  = a1;
        ds[SL(tid + 8192)]  = a2;  ds[SL(tid + 12288)] = a3;
        p4b<-1>(ds, tid + 1024, a0, a1, a2, a3);
        ds[SL(tid + 1024)]  = a0;  ds[SL(tid + 5120)]  = a1;
        ds[SL(tid + 9216)]  = a2;  ds[SL(tid + 13312)] = a3;
        p4b<-1>(ds, tid + 2048, a0, a1, a2, a3);
        ds[SL(tid + 2048)]  = a0;  ds[SL(tid + 6144)]  = a1;
        ds[SL(tid + 10240)] = a2;  ds[SL(tid + 14336)] = a3;
        p4b<-1>(ds, tid + 3072, a0, a1, a2, a3);
        ds[SL(tid + 3072)]  = a0;  ds[SL(tid + 7168)]  = a1;
        ds[SL(tid + 11264)] = a2;  ds[SL(tid + 15360)] = a3;
    }
    __syncthreads();

    // Z[j]=A[j]K[j], Z[M-j]=A[M-j]conj(K[j]); K from workspace (coalesced).
    {
        const float2* kc = kw + (size_t)c * KSTRIDE;
#pragma unroll
        for (int r = 0; r < 8; r++) {
            const int j  = tid + (r << 10);
            const int jm = (MFFT - j) & (MFFT - 1);
            float2 Kv = kc[j];
            float2 Aj = ds[SL(j)];
            float2 Am = ds[SL(jm)];
            ds[SL(j)]  = cmul(Aj, Kv);
            ds[SL(jm)] = cmul(Am, conjf2(Kv));     // j=0: K DC is real; OK
        }
        if (tid == 0) {
            float2 Kv = kc[8192];
            ds[SL(8192)] = cmul(ds[SL(8192)], Kv); // Nyquist
        }
    }
    __syncthreads();

    // inverse FFT
    P8FIRST_LDS(1)
    P8PASS(1, 8)
    P8PASS(1, 64)
    P8PASS(1, 512)
    // final inverse radix-4: only bins < LSEQ, straight to HBM.
    {
        float2 a0, a1, a2, a3;
        p4b<1>(ds, tid, a0, a1, a2, a3);
        y0p[tid]        = a0.x;  y1p[tid]        = a0.y;
        y0p[tid + 4096] = a1.x;  y1p[tid + 4096] = a1.y;
        p4b<1>(ds, tid + 1024, a0, a1, a2, a3);
        y0p[tid + 1024] = a0.x;  y1p[tid + 1024] = a0.y;
        y0p[tid + 5120] = a1.x;  y1p[tid + 5120] = a1.y;
        p4b<1>(ds, tid + 2048, a0, a1, a2, a3);
        y0p[tid + 2048] = a0.x;  y1p[tid + 2048] = a0.y;
        y0p[tid + 6144] = a1.x;  y1p[tid + 6144] = a1.y;
        p4b<1>(ds, tid + 3072, a0, a1, a2, a3);
        y0p[tid + 3072] = a0.x;  y1p[tid + 3072] = a0.y;
        y0p[tid + 7168] = a1.x;  y1p[tid + 7168] = a1.y;
    }
}

// ====== Fallback (ws too small): per (b,c), square trick, no K state ======
__global__ __launch_bounds__(NT)
void hyena_fb(const float* __restrict__ x, const float* __restrict__ k,
              const float* __restrict__ bias, float* __restrict__ y)
{
    __shared__ float2 ds[MFFT];
    const int bc = blockIdx.x, tid = threadIdx.x;
    const int c = bc & (CCH - 1);
    const float* xp = x + (size_t)bc * LSEQ;
    const float* kp = k + (size_t)c * LSEQ;
    float*       yp = y + (size_t)bc * LSEQ;
    const float b0 = bias[c];

    // forward pass0: pack x + i*k (bias into k tap 0).
    {
        float2 pa0 = make_float2(xp[tid], kp[tid]);
        if (tid == 0) pa0.y += b0;
        float2 pa1 = make_float2(xp[tid + 2048], kp[tid + 2048]);
        float2 pa2 = make_float2(xp[tid + 4096], kp[tid + 4096]);
        float2 pa3 = make_float2(xp[tid + 6144], kp[tid + 6144]);
        float2 pa4 = make_float2(0.f, 0.f), pa5 = make_float2(0.f, 0.f);
        float2 pa6 = make_float2(0.f, 0.f), pa7 = make_float2(0.f, 0.f);
        DFT8C(-1, pa)
        float2 pb0 = make_float2(xp[tid + 1024], kp[tid + 1024]);
        float2 pb1 = make_float2(xp[tid + 3072], kp[tid + 3072]);
        float2 pb2 = make_float2(xp[tid + 5120], kp[tid + 5120]);
        float2 pb3 = make_float2(xp[tid + 7168], kp[tid + 7168]);
        float2 pb4 = make_float2(0.f, 0.f), pb5 = make_float2(0.f, 0.f);
        float2 pb6 = make_float2(0.f, 0.f), pb7 = make_float2(0.f, 0.f);
        DFT8C(-1, pb)
        WR8(pa, tid, 1)
        WR8(pb, tid + 1024, 1)
        __syncthreads();
    }
    P8PASS(-1, 8)
    P8PASS(-1, 64)
    P8PASS(-1, 512)
    {
        float2 a0, a1, a2, a3;
        p4b<-1>(ds, tid, a0, a1, a2, a3);
        ds[SL(tid)]         = a0;  ds[SL(tid + 4096)]  = a1;
        ds[SL(tid + 8192)]  = a2;  ds[SL(tid + 12288)] = a3;
        p4b<-1>(ds, tid + 1024, a0, a1, a2, a3);
        ds[SL(tid + 1024)]  = a0;  ds[SL(tid + 5120)]  = a1;
        ds[SL(tid + 9216)]  = a2;  ds[SL(tid + 13312)] = a3;
        p4b<-1>(ds, tid + 2048, a0, a1, a2, a3);
        ds[SL(tid + 2048)]  = a0;  ds[SL(tid + 6144)]  = a1;
        ds[SL(tid + 10240)] = a2;  ds[SL(tid + 14336)] = a3;
        p4b<-1>(ds, tid + 3072, a0, a1, a2, a3);
        ds[SL(tid + 3072)]  = a0;  ds[SL(tid + 7168)]  = a1;
        ds[SL(tid + 11264)] = a2;  ds[SL(tid + 15360)] = a3;
    }
    __syncthreads();

    // X[j]K[j] = (-i/4)(C[j]^2 - conj(C[M-j])^2), scaled 1/M; Hermitian write.
    {
        const float sc = 1.0f / (4.0f * (float)MFFT);
#pragma unroll
        for (int r = 0; r < 8; r++) {
            const int j  = tid + (r << 10);
            const int jm = (MFFT - j) & (MFFT - 1);
            float2 Ca = ds[SL(j)];
            float2 Cb = ds[SL(jm)];
            float ar = Ca.x * Ca.x - Ca.y * Ca.y, ai = 2.f * Ca.x * Ca.y;
            float br = Cb.x * Cb.x - Cb.y * Cb.y, bi = 2.f * Cb.x * Cb.y;
            float wr = sc * (ai + bi);
            float wi = sc * (br - ar);
            ds[SL(j)]  = make_float2(wr,  wi);
            ds[SL(jm)] = make_float2(wr, -wi);
        }
        if (tid == 0) {
            float2 C8 = ds[SL(8192)];
            float ai = 2.f * C8.x * C8.y;
            ds[SL(8192)] = make_float2(sc * (ai + ai), 0.f);
        }
    }
    __syncthreads();

    P8FIRST_LDS(1)
    P8PASS(1, 8)
    P8PASS(1, 64)
    P8PASS(1, 512)
    {
        float2 a0, a1, a2, a3;
        p4b<1>(ds, tid, a0, a1, a2, a3);
        yp[tid]        = a0.x;
        yp[tid + 4096] = a1.x;
        p4b<1>(ds, tid + 1024, a0, a1, a2, a3);
        yp[tid + 1024] = a0.x;
        yp[tid + 5120] = a1.x;
        p4b<1>(ds, tid + 2048, a0, a1, a2, a3);
        yp[tid + 2048] = a0.x;
        yp[tid + 6144] = a1.x;
        p4b<1>(ds, tid + 3072, a0, a1, a2, a3);
        yp[tid + 3072] = a0.x;
        yp[tid + 7168] = a1.x;
    }
}

extern "C" void kernel_launch(void* const* d_in, const int* in_sizes, int n_in,
                              void* d_out, int out_size, void* d_ws, size_t ws_size,
                              hipStream_t stream) {
    const float* x    = (const float*)d_in[0];
    const float* k    = (const float*)d_in[1];
    const float* bias = (const float*)d_in[2];
    float* y          = (float*)d_out;

    const size_t need = (size_t)CCH * KSTRIDE * sizeof(float2);   // ~134 MB
    if (ws_size >= need) {
        float2* kw = (float2*)d_ws;
        hyena_kfft <<<dim3(CCH),     dim3(NT), 0, stream>>>(k, bias, kw);
        hyena_xconv<<<dim3(CCH),     dim3(NT), 0, stream>>>(x, kw, y);
    } else {
        hyena_fb   <<<dim3(2 * CCH), dim3(NT), 0, stream>>>(x, k, bias, y);
    }
}

// Round 9
// 246.426 us; speedup vs baseline: 2.0228x; 1.1086x over previous
//
#include <hip/hip_runtime.h>

#define LSEQ 8192
#define MFFT 16384      // 2*L = 8*8*8*8*4
#define NT 1024
#define CCH 2048
#define TWO_PI 6.283185307179586f
#define KSTRIDE 8208    // float2 stride per channel in workspace (>=8193, mult of 16)

// Parity-preserving XOR swizzle: XOR value is even, so {2m,2m+1} -> {q,q+1}
// (adjacent, 16B-aligned). Verified conflict-free per 16-lane group for all
// pass patterns (stride-2048 reads, NS=1/8/64/512 scatters, radix-4 final).
__device__ __forceinline__ int SL2(int i) { return i ^ (((i >> 4) & 15) << 1); }

__device__ __forceinline__ float2 cmul(float2 a, float2 b) {
    return make_float2(fmaf(a.x, b.x, -a.y * b.y), fmaf(a.x, b.y, a.y * b.x));
}
__device__ __forceinline__ float2 conjf2(float2 a) { return make_float2(a.x, -a.y); }
__device__ __forceinline__ float2 scalef2(float2 a, float s) { return make_float2(a.x * s, a.y * s); }

template<int SGN>
__device__ __forceinline__ void dft4(float2& a0, float2& a1, float2& a2, float2& a3) {
    float t0x = a0.x + a2.x, t0y = a0.y + a2.y;
    float t1x = a0.x - a2.x, t1y = a0.y - a2.y;
    float t2x = a1.x + a3.x, t2y = a1.y + a3.y;
    float t3x = a1.x - a3.x, t3y = a1.y - a3.y;
    float ux = (SGN < 0) ? t3y : -t3y;   // u = SGN*i*t3
    float uy = (SGN < 0) ? -t3x : t3x;
    a0 = make_float2(t0x + t2x, t0y + t2y);
    a1 = make_float2(t1x + ux, t1y + uy);
    a2 = make_float2(t0x - t2x, t0y - t2y);
    a3 = make_float2(t1x - ux, t1y - uy);
}

// Natural-order 8-point DFT (DIT: evens/odds dft4 + W8 combine).
template<int SGN>
__device__ __forceinline__ void dft8(float2& v0, float2& v1, float2& v2, float2& v3,
                                     float2& v4, float2& v5, float2& v6, float2& v7) {
    float2 e0 = v0, e1 = v2, e2 = v4, e3 = v6;
    float2 o0 = v1, o1 = v3, o2 = v5, o3 = v7;
    dft4<SGN>(e0, e1, e2, e3);
    dft4<SGN>(o0, o1, o2, o3);
    const float sg = (float)SGN;
    const float H = 0.7071067811865476f;
    float2 t1 = cmul(o1, make_float2( H, sg * H));
    float2 t2 = make_float2(-sg * o2.y, sg * o2.x);        // o2 * W8^2
    float2 t3 = cmul(o3, make_float2(-H, sg * H));
    v0 = make_float2(e0.x + o0.x, e0.y + o0.y);
    v4 = make_float2(e0.x - o0.x, e0.y - o0.y);
    v1 = make_float2(e1.x + t1.x, e1.y + t1.y);
    v5 = make_float2(e1.x - t1.x, e1.y - t1.y);
    v2 = make_float2(e2.x + t2.x, e2.y + t2.y);
    v6 = make_float2(e2.x - t2.x, e2.y - t2.y);
    v3 = make_float2(e3.x + t3.x, e3.y + t3.y);
    v7 = make_float2(e3.x - t3.x, e3.y - t3.y);
}

// b128 paired LDS ops: logical elements {e, e+1} (e even).
__device__ __forceinline__ void rdp(const float2* ds, int e, float2& lo, float2& hi) {
    const float4 v = *reinterpret_cast<const float4*>(&ds[SL2(e)]);
    lo = make_float2(v.x, v.y);
    hi = make_float2(v.z, v.w);
}
__device__ __forceinline__ void wrp(float2* ds, int e, float2 lo, float2 hi) {
    *reinterpret_cast<float4*>(&ds[SL2(e)]) = make_float4(lo.x, lo.y, hi.x, hi.y);
}
__device__ __forceinline__ void st4(float2* p, float2 lo, float2 hi) {
    *reinterpret_cast<float4*>(p) = make_float4(lo.x, lo.y, hi.x, hi.y);
}

// Paired reads at Stockham stride 2048: a_r = elem(B_+2048r), b_r = elem(B_+1+2048r).
#define RD8P                                                                  \
    float2 a0,a1,a2,a3,a4,a5,a6,a7,b0,b1,b2,b3,b4,b5,b6,b7;                   \
    rdp(ds, B_,         a0, b0);                                              \
    rdp(ds, B_ +  2048, a1, b1);                                              \
    rdp(ds, B_ +  4096, a2, b2);                                              \
    rdp(ds, B_ +  6144, a3, b3);                                              \
    rdp(ds, B_ +  8192, a4, b4);                                              \
    rdp(ds, B_ + 10240, a5, b5);                                              \
    rdp(ds, B_ + 12288, a6, b6);                                              \
    rdp(ds, B_ + 14336, a7, b7);

#define DFT8AB(SGN)                                                           \
    dft8<(SGN)>(a0,a1,a2,a3,a4,a5,a6,a7);                                     \
    dft8<(SGN)>(b0,b1,b2,b3,b4,b5,b6,b7);

// One sincos for butterfly B_; butterfly B_+1's base twiddle = wa * wD
// (wD = e^{SGN*2pi i/(8*NS)}, compile-time constant per pass).
#define TWID(SGN, NSv, WDC, WDS) {                                            \
    float s_, c_;                                                             \
    __sincosf((float)(SGN) * TWO_PI / (float)((NSv) * 8) *                    \
              (float)(B_ & ((NSv) - 1)), &s_, &c_);                           \
    const float2 wa = make_float2(c_, s_);                                    \
    const float2 wb = cmul(wa, make_float2((WDC), (float)(SGN) * (WDS)));     \
    float2 wc = wa;                                                           \
    a1 = cmul(a1, wc);                                                        \
    wc = cmul(wc, wa); a2 = cmul(a2, wc);                                     \
    wc = cmul(wc, wa); a3 = cmul(a3, wc);                                     \
    wc = cmul(wc, wa); a4 = cmul(a4, wc);                                     \
    wc = cmul(wc, wa); a5 = cmul(a5, wc);                                     \
    wc = cmul(wc, wa); a6 = cmul(a6, wc);                                     \
    wc = cmul(wc, wa); a7 = cmul(a7, wc);                                     \
    wc = wb;                                                                  \
    b1 = cmul(b1, wc);                                                        \
    wc = cmul(wc, wb); b2 = cmul(b2, wc);                                     \
    wc = cmul(wc, wb); b3 = cmul(b3, wc);                                     \
    wc = cmul(wc, wb); b4 = cmul(b4, wc);                                     \
    wc = cmul(wc, wb); b5 = cmul(b5, wc);                                     \
    wc = cmul(wc, wb); b6 = cmul(b6, wc);                                     \
    wc = cmul(wc, wb); b7 = cmul(b7, wc);                                     \
}

// Stockham scatter: butterfly B_ r-th out -> d_+NS*r; butterfly B_+1 -> d_+1+NS*r.
#define WR8P(NSv) {                                                           \
    const int i_ = B_ & ((NSv) - 1);                                          \
    const int d_ = ((B_ - i_) << 3) + i_;                                     \
    wrp(ds, d_,             a0, b0);                                          \
    wrp(ds, d_ +     (NSv), a1, b1);                                          \
    wrp(ds, d_ + 2 * (NSv), a2, b2);                                          \
    wrp(ds, d_ + 3 * (NSv), a3, b3);                                          \
    wrp(ds, d_ + 4 * (NSv), a4, b4);                                          \
    wrp(ds, d_ + 5 * (NSv), a5, b5);                                          \
    wrp(ds, d_ + 6 * (NSv), a6, b6);                                          \
    wrp(ds, d_ + 7 * (NSv), a7, b7);                                          \
}

// NS=1 writes: butterfly B_'s 8 outputs land at 8*B_..+7 (sequential).
#define WR8SEQ {                                                              \
    const int d_ = B_ << 3;                                                   \
    wrp(ds, d_,      a0, a1);                                                 \
    wrp(ds, d_ +  2, a2, a3);                                                 \
    wrp(ds, d_ +  4, a4, a5);                                                 \
    wrp(ds, d_ +  6, a6, a7);                                                 \
    wrp(ds, d_ +  8, b0, b1);                                                 \
    wrp(ds, d_ + 10, b2, b3);                                                 \
    wrp(ds, d_ + 12, b4, b5);                                                 \
    wrp(ds, d_ + 14, b6, b7);                                                 \
}

#define P8MID(SGN, NSv, WDC, WDS) {                                           \
    RD8P                                                                      \
    TWID(SGN, NSv, WDC, WDS)                                                  \
    DFT8AB(SGN)                                                               \
    __syncthreads();                                                          \
    WR8P(NSv)                                                                 \
    __syncthreads();                                                          \
}

#define P8FIRST(SGN) {                                                        \
    RD8P                                                                      \
    DFT8AB(SGN)                                                               \
    __syncthreads();                                                          \
    WR8SEQ                                                                    \
    __syncthreads();                                                          \
}

// WD constants: e^{2pi/(8*NS)} for NS = 8 / 64 / 512.
#define WD8C  0.9951847266721969f
#define WD8S  0.0980171403295606f
#define WD64C 0.9999247018391445f
#define WD64S 0.012271538285719925f
#define WD512C 0.9999988234517019f
#define WD512S 0.0015339801862847655f

// Final radix-4 paired butterfly (jj even): A* for bin-set of jj, B* for jj+1.
template<int SGN>
__device__ __forceinline__ void p4pair(const float2* ds, int jj,
        float2& A0, float2& A1, float2& A2, float2& A3,
        float2& B0, float2& B1, float2& B2, float2& B3) {
    rdp(ds, jj,         A0, B0);
    rdp(ds, jj +  4096, A1, B1);
    rdp(ds, jj +  8192, A2, B2);
    rdp(ds, jj + 12288, A3, B3);
    float s1, c1;
    __sincosf((float)SGN * TWO_PI / (float)MFFT * (float)jj, &s1, &c1);
    const float2 wa = make_float2(c1, s1);
    const float2 wb = cmul(wa, make_float2(0.9999999264657179f,
                         (float)SGN * 3.8349518757139556e-4f));
    float2 w2 = cmul(wa, wa), w3 = cmul(w2, wa);
    A1 = cmul(A1, wa); A2 = cmul(A2, w2); A3 = cmul(A3, w3);
    w2 = cmul(wb, wb); w3 = cmul(w2, wb);
    B1 = cmul(B1, wb); B2 = cmul(B2, w2); B3 = cmul(B3, w3);
    dft4<SGN>(A0, A1, A2, A3);
    dft4<SGN>(B0, B1, B2, B3);
}

// ===================== Kernel A: K spectrum -> workspace =====================
__global__ __launch_bounds__(NT)
void hyena_kfft(const float* __restrict__ k, const float* __restrict__ bias,
                float2* __restrict__ kw)
{
    __shared__ alignas(16) float2 ds[MFFT];
    const int c = blockIdx.x, tid = threadIdx.x;
    const int B_ = tid << 1;
    const float* kp = k + (size_t)c * LSEQ;
    const float bsv = bias[c];

    {   // pass0 (NS=1) from global; top half of padded input is zero.
        float2 a0,a1,a2,a3,a4,a5,a6,a7,b0,b1,b2,b3,b4,b5,b6,b7;
        float2 kv;
        kv = *(const float2*)&kp[B_];
        a0 = make_float2(kv.x, 0.f); b0 = make_float2(kv.y, 0.f);
        if (tid == 0) a0.x += bsv;                 // bias = conv tap s=0
        kv = *(const float2*)&kp[B_ + 2048];
        a1 = make_float2(kv.x, 0.f); b1 = make_float2(kv.y, 0.f);
        kv = *(const float2*)&kp[B_ + 4096];
        a2 = make_float2(kv.x, 0.f); b2 = make_float2(kv.y, 0.f);
        kv = *(const float2*)&kp[B_ + 6144];
        a3 = make_float2(kv.x, 0.f); b3 = make_float2(kv.y, 0.f);
        a4 = a5 = a6 = a7 = b4 = b5 = b6 = b7 = make_float2(0.f, 0.f);
        DFT8AB(-1)
        WR8SEQ
        __syncthreads();
    }
    P8MID(-1, 8,   WD8C,   WD8S)
    P8MID(-1, 64,  WD64C,  WD64S)
    P8MID(-1, 512, WD512C, WD512S)

    {   // final radix-4; write Hermitian half (bins 0..8192) scaled by 1/M.
        const float sc = 1.0f / (float)MFFT;
        float2* kc = kw + (size_t)c * KSTRIDE;
        float2 A0,A1,A2,A3,B0,B1,B2,B3;
        int jj = B_;
        p4pair<-1>(ds, jj, A0,A1,A2,A3,B0,B1,B2,B3);
        st4(kc + jj,        scalef2(A0, sc), scalef2(B0, sc));
        st4(kc + jj + 4096, scalef2(A1, sc), scalef2(B1, sc));
        if (tid == 0) kc[8192] = scalef2(A2, sc);   // Nyquist
        jj = B_ + 2048;
        p4pair<-1>(ds, jj, A0,A1,A2,A3,B0,B1,B2,B3);
        st4(kc + jj,        scalef2(A0, sc), scalef2(B0, sc));
        st4(kc + jj + 4096, scalef2(A1, sc), scalef2(B1, sc));
    }
}

// ============ Kernel B: A=FFT(x0+i*x1), Z=A*K, y0=Re(IFFT), y1=Im ============
__global__ __launch_bounds__(NT)
void hyena_xconv(const float* __restrict__ x, const float2* __restrict__ kw,
                 float* __restrict__ y)
{
    __shared__ alignas(16) float2 ds[MFFT];
    const int c = blockIdx.x, tid = threadIdx.x;
    const int B_ = tid << 1;
    const float* x0p = x + (size_t)c * LSEQ;
    const float* x1p = x + ((size_t)(CCH + c)) * LSEQ;
    float*       y0p = y + (size_t)c * LSEQ;
    float*       y1p = y + ((size_t)(CCH + c)) * LSEQ;

    {   // forward pass0 (NS=1) straight from global.
        float2 a0,a1,a2,a3,a4,a5,a6,a7,b0,b1,b2,b3,b4,b5,b6,b7;
        float2 xa, xb;
        xa = *(const float2*)&x0p[B_];        xb = *(const float2*)&x1p[B_];
        a0 = make_float2(xa.x, xb.x); b0 = make_float2(xa.y, xb.y);
        xa = *(const float2*)&x0p[B_ + 2048]; xb = *(const float2*)&x1p[B_ + 2048];
        a1 = make_float2(xa.x, xb.x); b1 = make_float2(xa.y, xb.y);
        xa = *(const float2*)&x0p[B_ + 4096]; xb = *(const float2*)&x1p[B_ + 4096];
        a2 = make_float2(xa.x, xb.x); b2 = make_float2(xa.y, xb.y);
        xa = *(const float2*)&x0p[B_ + 6144]; xb = *(const float2*)&x1p[B_ + 6144];
        a3 = make_float2(xa.x, xb.x); b3 = make_float2(xa.y, xb.y);
        a4 = a5 = a6 = a7 = b4 = b5 = b6 = b7 = make_float2(0.f, 0.f);
        DFT8AB(-1)
        WR8SEQ
        __syncthreads();
    }
    P8MID(-1, 8,   WD8C,   WD8S)
    P8MID(-1, 64,  WD64C,  WD64S)
    P8MID(-1, 512, WD512C, WD512S)

    {   // final forward radix-4, in place (class-local partition by j).
        float2 A0,A1,A2,A3,B0,B1,B2,B3;
        int jj = B_;
        p4pair<-1>(ds, jj, A0,A1,A2,A3,B0,B1,B2,B3);
        wrp(ds, jj,         A0, B0);
        wrp(ds, jj +  4096, A1, B1);
        wrp(ds, jj +  8192, A2, B2);
        wrp(ds, jj + 12288, A3, B3);
        jj = B_ + 2048;
        p4pair<-1>(ds, jj, A0,A1,A2,A3,B0,B1,B2,B3);
        wrp(ds, jj,         A0, B0);
        wrp(ds, jj +  4096, A1, B1);
        wrp(ds, jj +  8192, A2, B2);
        wrp(ds, jj + 12288, A3, B3);
    }
    __syncthreads();

    {   // Z[j]=A[j]K[j], Z[M-j]=A[M-j]conj(K[j]); K half-spectrum (coalesced).
        const float2* kc = kw + (size_t)c * KSTRIDE;
        if (tid == 0) {
            ds[SL2(0)]    = cmul(ds[SL2(0)],    kc[0]);      // DC
            ds[SL2(8192)] = cmul(ds[SL2(8192)], kc[8192]);   // Nyquist
        } else {
            const int jm = MFFT - tid;
            float2 Kv = kc[tid];
            float2 Aj = ds[SL2(tid)];
            float2 Am = ds[SL2(jm)];
            ds[SL2(tid)] = cmul(Aj, Kv);
            ds[SL2(jm)]  = cmul(Am, conjf2(Kv));
        }
#pragma unroll
        for (int r = 1; r < 8; r++) {
            const int j  = tid + (r << 10);
            const int jm = MFFT - j;
            float2 Kv = kc[j];
            float2 Aj = ds[SL2(j)];
            float2 Am = ds[SL2(jm)];
            ds[SL2(j)]  = cmul(Aj, Kv);
            ds[SL2(jm)] = cmul(Am, conjf2(Kv));
        }
    }
    __syncthreads();

    // inverse FFT
    P8FIRST(1)
    P8MID(1, 8,   WD8C,   WD8S)
    P8MID(1, 64,  WD64C,  WD64S)
    P8MID(1, 512, WD512C, WD512S)

    {   // final inverse radix-4: only bins < LSEQ, paired float2 stores to HBM.
        float2 A0,A1,A2,A3,B0,B1,B2,B3;
        int jj = B_;
        p4pair<1>(ds, jj, A0,A1,A2,A3,B0,B1,B2,B3);
        *(float2*)&y0p[jj]        = make_float2(A0.x, B0.x);
        *(float2*)&y1p[jj]        = make_float2(A0.y, B0.y);
        *(float2*)&y0p[jj + 4096] = make_float2(A1.x, B1.x);
        *(float2*)&y1p[jj + 4096] = make_float2(A1.y, B1.y);
        jj = B_ + 2048;
        p4pair<1>(ds, jj, A0,A1,A2,A3,B0,B1,B2,B3);
        *(float2*)&y0p[jj]        = make_float2(A0.x, B0.x);
        *(float2*)&y1p[jj]        = make_float2(A0.y, B0.y);
        *(float2*)&y0p[jj + 4096] = make_float2(A1.x, B1.x);
        *(float2*)&y1p[jj + 4096] = make_float2(A1.y, B1.y);
    }
}

extern "C" void kernel_launch(void* const* d_in, const int* in_sizes, int n_in,
                              void* d_out, int out_size, void* d_ws, size_t ws_size,
                              hipStream_t stream) {
    const float* x    = (const float*)d_in[0];
    const float* k    = (const float*)d_in[1];
    const float* bias = (const float*)d_in[2];
    float* y          = (float*)d_out;
    float2* kw        = (float2*)d_ws;   // ws_size >= 134 MB (verified in R8: two-kernel path ran)

    hyena_kfft <<<dim3(CCH), dim3(NT), 0, stream>>>(k, bias, kw);
    hyena_xconv<<<dim3(CCH), dim3(NT), 0, stream>>>(x, kw, y);
}

// Round 10
// 195.498 us; speedup vs baseline: 2.5498x; 1.2605x over previous
//
#include <hip/hip_runtime.h>

#define LSEQ 8192
#define NFFT 8192       // half-size complex FFT via even/odd real packing
#define NT2 512
#define CCH 2048
#define TWO_PI 6.283185307179586f
#define PI_F  3.14159265358979323846f
#define KSTRIDE 8208    // float2 stride per channel in workspace (>=8193)

// Parity-preserving XOR swizzle (same family as R9, verified conflict-free).
__device__ __forceinline__ int SL2(int i) { return i ^ (((i >> 4) & 15) << 1); }

__device__ __forceinline__ float2 cmul(float2 a, float2 b) {
    return make_float2(fmaf(a.x, b.x, -a.y * b.y), fmaf(a.x, b.y, a.y * b.x));
}
__device__ __forceinline__ float2 conjf2(float2 a) { return make_float2(a.x, -a.y); }

template<int SGN>
__device__ __forceinline__ void dft4(float2& a0, float2& a1, float2& a2, float2& a3) {
    float t0x = a0.x + a2.x, t0y = a0.y + a2.y;
    float t1x = a0.x - a2.x, t1y = a0.y - a2.y;
    float t2x = a1.x + a3.x, t2y = a1.y + a3.y;
    float t3x = a1.x - a3.x, t3y = a1.y - a3.y;
    float ux = (SGN < 0) ? t3y : -t3y;   // u = SGN*i*t3
    float uy = (SGN < 0) ? -t3x : t3x;
    a0 = make_float2(t0x + t2x, t0y + t2y);
    a1 = make_float2(t1x + ux, t1y + uy);
    a2 = make_float2(t0x - t2x, t0y - t2y);
    a3 = make_float2(t1x - ux, t1y - uy);
}

template<int SGN>
__device__ __forceinline__ void dft8(float2& v0, float2& v1, float2& v2, float2& v3,
                                     float2& v4, float2& v5, float2& v6, float2& v7) {
    float2 e0 = v0, e1 = v2, e2 = v4, e3 = v6;
    float2 o0 = v1, o1 = v3, o2 = v5, o3 = v7;
    dft4<SGN>(e0, e1, e2, e3);
    dft4<SGN>(o0, o1, o2, o3);
    const float sg = (float)SGN;
    const float H = 0.7071067811865476f;
    float2 t1 = cmul(o1, make_float2( H, sg * H));
    float2 t2 = make_float2(-sg * o2.y, sg * o2.x);
    float2 t3 = cmul(o3, make_float2(-H, sg * H));
    v0 = make_float2(e0.x + o0.x, e0.y + o0.y);
    v4 = make_float2(e0.x - o0.x, e0.y - o0.y);
    v1 = make_float2(e1.x + t1.x, e1.y + t1.y);
    v5 = make_float2(e1.x - t1.x, e1.y - t1.y);
    v2 = make_float2(e2.x + t2.x, e2.y + t2.y);
    v6 = make_float2(e2.x - t2.x, e2.y - t2.y);
    v3 = make_float2(e3.x + t3.x, e3.y + t3.y);
    v7 = make_float2(e3.x - t3.x, e3.y - t3.y);
}

// b128 paired LDS ops for logical elements {e, e+1} (e even).
__device__ __forceinline__ void rdp(const float2* ds, int e, float2& lo, float2& hi) {
    const float4 v = *reinterpret_cast<const float4*>(&ds[SL2(e)]);
    lo = make_float2(v.x, v.y);
    hi = make_float2(v.z, v.w);
}
__device__ __forceinline__ void wrp(float2* ds, int e, float2 lo, float2 hi) {
    *reinterpret_cast<float4*>(&ds[SL2(e)]) = make_float4(lo.x, lo.y, hi.x, hi.y);
}

// Radix-8 Stockham reads at stride NFFT/8 = 1024, butterflies {B_, B_+1}.
#define RD8X                                                                  \
    float2 a0,a1,a2,a3,a4,a5,a6,a7,b0,b1,b2,b3,b4,b5,b6,b7;                   \
    rdp(ds, B_,        a0, b0);                                               \
    rdp(ds, B_ + 1024, a1, b1);                                               \
    rdp(ds, B_ + 2048, a2, b2);                                               \
    rdp(ds, B_ + 3072, a3, b3);                                               \
    rdp(ds, B_ + 4096, a4, b4);                                               \
    rdp(ds, B_ + 5120, a5, b5);                                               \
    rdp(ds, B_ + 6144, a6, b6);                                               \
    rdp(ds, B_ + 7168, a7, b7);

#define DFT8AB(SGN)                                                           \
    dft8<(SGN)>(a0,a1,a2,a3,a4,a5,a6,a7);                                     \
    dft8<(SGN)>(b0,b1,b2,b3,b4,b5,b6,b7);

// One sincos per thread; butterfly B_+1 base twiddle = wa * wD (constant).
#define TWID(SGN, NSv, WDC, WDS) {                                            \
    float s_, c_;                                                             \
    __sincosf((float)(SGN) * TWO_PI / (float)((NSv) * 8) *                    \
              (float)(B_ & ((NSv) - 1)), &s_, &c_);                           \
    const float2 wa = make_float2(c_, s_);                                    \
    const float2 wb = cmul(wa, make_float2((WDC), (float)(SGN) * (WDS)));     \
    float2 wc = wa;                                                           \
    a1 = cmul(a1, wc);                                                        \
    wc = cmul(wc, wa); a2 = cmul(a2, wc);                                     \
    wc = cmul(wc, wa); a3 = cmul(a3, wc);                                     \
    wc = cmul(wc, wa); a4 = cmul(a4, wc);                                     \
    wc = cmul(wc, wa); a5 = cmul(a5, wc);                                     \
    wc = cmul(wc, wa); a6 = cmul(a6, wc);                                     \
    wc = cmul(wc, wa); a7 = cmul(a7, wc);                                     \
    wc = wb;                                                                  \
    b1 = cmul(b1, wc);                                                        \
    wc = cmul(wc, wb); b2 = cmul(b2, wc);                                     \
    wc = cmul(wc, wb); b3 = cmul(b3, wc);                                     \
    wc = cmul(wc, wb); b4 = cmul(b4, wc);                                     \
    wc = cmul(wc, wb); b5 = cmul(b5, wc);                                     \
    wc = cmul(wc, wb); b6 = cmul(b6, wc);                                     \
    wc = cmul(wc, wb); b7 = cmul(b7, wc);                                     \
}

#define WR8P(NSv) {                                                           \
    const int i_ = B_ & ((NSv) - 1);                                          \
    const int d_ = ((B_ - i_) << 3) + i_;                                     \
    wrp(ds, d_,             a0, b0);                                          \
    wrp(ds, d_ +     (NSv), a1, b1);                                          \
    wrp(ds, d_ + 2 * (NSv), a2, b2);                                          \
    wrp(ds, d_ + 3 * (NSv), a3, b3);                                          \
    wrp(ds, d_ + 4 * (NSv), a4, b4);                                          \
    wrp(ds, d_ + 5 * (NSv), a5, b5);                                          \
    wrp(ds, d_ + 6 * (NSv), a6, b6);                                          \
    wrp(ds, d_ + 7 * (NSv), a7, b7);                                          \
}

#define WR8SEQ {                                                              \
    const int d_ = B_ << 3;                                                   \
    wrp(ds, d_,      a0, a1);                                                 \
    wrp(ds, d_ +  2, a2, a3);                                                 \
    wrp(ds, d_ +  4, a4, a5);                                                 \
    wrp(ds, d_ +  6, a6, a7);                                                 \
    wrp(ds, d_ +  8, b0, b1);                                                 \
    wrp(ds, d_ + 10, b2, b3);                                                 \
    wrp(ds, d_ + 12, b4, b5);                                                 \
    wrp(ds, d_ + 14, b6, b7);                                                 \
}

#define P8MID(SGN, NSv, WDC, WDS) {                                           \
    RD8X                                                                      \
    TWID(SGN, NSv, WDC, WDS)                                                  \
    DFT8AB(SGN)                                                               \
    __syncthreads();                                                          \
    WR8P(NSv)                                                                 \
    __syncthreads();                                                          \
}

#define P8FIRST_LDS(SGN) {                                                    \
    RD8X                                                                      \
    DFT8AB(SGN)                                                               \
    __syncthreads();                                                          \
    WR8SEQ                                                                    \
    __syncthreads();                                                          \
}

// wD = e^{2pi/(8*NS)} for NS = 8 / 64.
#define WD8C  0.9951847266721969f
#define WD8S  0.0980171403295606f
#define WD64C 0.9999247018391445f
#define WD64S 0.012271538285719925f

// Radix-16 DFT over named float2 scalars; X[k] ends in P{4*(k&3)+(k>>2)}.
#define DFT16M(SGN, P) {                                                            \
    dft4<(SGN)>(P##0, P##4, P##8,  P##12);                                          \
    dft4<(SGN)>(P##1, P##5, P##9,  P##13);                                          \
    dft4<(SGN)>(P##2, P##6, P##10, P##14);                                          \
    dft4<(SGN)>(P##3, P##7, P##11, P##15);                                          \
    const float sg_ = (float)(SGN);                                                 \
    const float2 tw1_ = make_float2( 0.9238795325112867f,  sg_ * 0.3826834323650898f); \
    const float2 tw2_ = make_float2( 0.7071067811865476f,  sg_ * 0.7071067811865476f); \
    const float2 tw3_ = make_float2( 0.3826834323650898f,  sg_ * 0.9238795325112867f); \
    const float2 tw6_ = make_float2(-0.7071067811865476f,  sg_ * 0.7071067811865476f); \
    const float2 tw9_ = make_float2(-0.9238795325112867f, -sg_ * 0.3826834323650898f); \
    P##5  = cmul(P##5,  tw1_);                                                      \
    P##6  = cmul(P##6,  tw2_);                                                      \
    P##7  = cmul(P##7,  tw3_);                                                      \
    P##9  = cmul(P##9,  tw2_);                                                      \
    P##10 = make_float2(-sg_ * (P##10).y, sg_ * (P##10).x);                         \
    P##11 = cmul(P##11, tw6_);                                                      \
    P##13 = cmul(P##13, tw3_);                                                      \
    P##14 = cmul(P##14, tw6_);                                                      \
    P##15 = cmul(P##15, tw9_);                                                      \
    dft4<(SGN)>(P##0,  P##1,  P##2,  P##3);                                         \
    dft4<(SGN)>(P##4,  P##5,  P##6,  P##7);                                         \
    dft4<(SGN)>(P##8,  P##9,  P##10, P##11);                                        \
    dft4<(SGN)>(P##12, P##13, P##14, P##15);                                        \
}

// Final radix-16 pass (NS=512): load class {tid+512r}, twiddle w^r, DFT16.
#define R16_LOAD_TWIDDLE(SGN)                                                 \
    float2 m0  = ds[SL2(tid)];                                                \
    float2 m1  = ds[SL2(tid +  512)];                                         \
    float2 m2  = ds[SL2(tid + 1024)];                                         \
    float2 m3  = ds[SL2(tid + 1536)];                                         \
    float2 m4  = ds[SL2(tid + 2048)];                                         \
    float2 m5  = ds[SL2(tid + 2560)];                                         \
    float2 m6  = ds[SL2(tid + 3072)];                                         \
    float2 m7  = ds[SL2(tid + 3584)];                                         \
    float2 m8  = ds[SL2(tid + 4096)];                                         \
    float2 m9  = ds[SL2(tid + 4608)];                                         \
    float2 m10 = ds[SL2(tid + 5120)];                                         \
    float2 m11 = ds[SL2(tid + 5632)];                                         \
    float2 m12 = ds[SL2(tid + 6144)];                                         \
    float2 m13 = ds[SL2(tid + 6656)];                                         \
    float2 m14 = ds[SL2(tid + 7168)];                                         \
    float2 m15 = ds[SL2(tid + 7680)];                                         \
    {                                                                         \
        float s_, c_;                                                         \
        __sincosf((float)(SGN) * TWO_PI / 8192.0f * (float)tid, &s_, &c_);    \
        const float2 w1_ = make_float2(c_, s_);                               \
        float2 wc_ = w1_;                                                     \
        m1  = cmul(m1,  wc_);                                                 \
        wc_ = cmul(wc_, w1_); m2  = cmul(m2,  wc_);                           \
        wc_ = cmul(wc_, w1_); m3  = cmul(m3,  wc_);                           \
        wc_ = cmul(wc_, w1_); m4  = cmul(m4,  wc_);                           \
        wc_ = cmul(wc_, w1_); m5  = cmul(m5,  wc_);                           \
        wc_ = cmul(wc_, w1_); m6  = cmul(m6,  wc_);                           \
        wc_ = cmul(wc_, w1_); m7  = cmul(m7,  wc_);                           \
        wc_ = cmul(wc_, w1_); m8  = cmul(m8,  wc_);                           \
        wc_ = cmul(wc_, w1_); m9  = cmul(m9,  wc_);                           \
        wc_ = cmul(wc_, w1_); m10 = cmul(m10, wc_);                           \
        wc_ = cmul(wc_, w1_); m11 = cmul(m11, wc_);                           \
        wc_ = cmul(wc_, w1_); m12 = cmul(m12, wc_);                           \
        wc_ = cmul(wc_, w1_); m13 = cmul(m13, wc_);                           \
        wc_ = cmul(wc_, w1_); m14 = cmul(m14, wc_);                           \
        wc_ = cmul(wc_, w1_); m15 = cmul(m15, wc_);                           \
    }

// Natural-order write-back of r16 outputs (slot tid+512k <- m{4*(k&3)+(k>>2)}).
#define R16_STORE_LDS                                                         \
    ds[SL2(tid)]        = m0;                                                 \
    ds[SL2(tid +  512)] = m4;                                                 \
    ds[SL2(tid + 1024)] = m8;                                                 \
    ds[SL2(tid + 1536)] = m12;                                                \
    ds[SL2(tid + 2048)] = m1;                                                 \
    ds[SL2(tid + 2560)] = m5;                                                 \
    ds[SL2(tid + 3072)] = m9;                                                 \
    ds[SL2(tid + 3584)] = m13;                                                \
    ds[SL2(tid + 4096)] = m2;                                                 \
    ds[SL2(tid + 4608)] = m6;                                                 \
    ds[SL2(tid + 5120)] = m10;                                                \
    ds[SL2(tid + 5632)] = m14;                                                \
    ds[SL2(tid + 6144)] = m3;                                                 \
    ds[SL2(tid + 6656)] = m7;                                                 \
    ds[SL2(tid + 7168)] = m11;                                                \
    ds[SL2(tid + 7680)] = m15;

// ================= Kernel A: K half-spectrum (16384 rfft) -> workspace =================
__global__ __launch_bounds__(NT2)
void hyena_kfft8(const float* __restrict__ k, const float* __restrict__ bias,
                 float2* __restrict__ kw)
{
    __shared__ alignas(16) float2 ds[NFFT];       // 64 KiB -> 2 blocks/CU
    const int c = blockIdx.x, tid = threadIdx.x;
    const int B_ = tid << 1;
    const float* kp = k + (size_t)c * LSEQ;
    const float bsv = bias[c];

    {   // pass0 (NS=1): w[e] = k[2e] + i*k[2e+1]; e >= 4096 is zero padding.
        float2 a0,a1,a2,a3,a4,a5,a6,a7,b0,b1,b2,b3,b4,b5,b6,b7;
        float4 v;
        v = *(const float4*)&kp[(B_ << 1)];
        a0 = make_float2(v.x, v.y); b0 = make_float2(v.z, v.w);
        if (tid == 0) a0.x += bsv;                 // bias = conv tap s=0
        v = *(const float4*)&kp[(B_ << 1) + 2048];
        a1 = make_float2(v.x, v.y); b1 = make_float2(v.z, v.w);
        v = *(const float4*)&kp[(B_ << 1) + 4096];
        a2 = make_float2(v.x, v.y); b2 = make_float2(v.z, v.w);
        v = *(const float4*)&kp[(B_ << 1) + 6144];
        a3 = make_float2(v.x, v.y); b3 = make_float2(v.z, v.w);
        a4 = a5 = a6 = a7 = b4 = b5 = b6 = b7 = make_float2(0.f, 0.f);
        DFT8AB(-1)
        WR8SEQ
        __syncthreads();
    }
    P8MID(-1, 8,  WD8C,  WD8S)
    P8MID(-1, 64, WD64C, WD64S)
    {   // final radix-16 (NS=512), in place (class-local).
        R16_LOAD_TWIDDLE(-1)
        DFT16M(-1, m)
        R16_STORE_LDS
    }
    __syncthreads();

    // Untangle to K[j] = rfft16384(k)[j] * (1/16384), j = 0..8192.
    {
        const float sc = 1.0f / 16384.0f;
        float2* kc = kw + (size_t)c * KSTRIDE;
#pragma unroll
        for (int r = 0; r < 8; r++) {
            const int j = tid + (r << 9);
            if (j == 0) {
                float2 W0 = ds[SL2(0)];
                kc[0]    = make_float2((W0.x + W0.y) * sc, 0.f);
                kc[8192] = make_float2((W0.x - W0.y) * sc, 0.f);
                float2 W4 = ds[SL2(4096)];
                kc[4096] = make_float2(W4.x * sc, -W4.y * sc);   // conj(W)*sc
            } else {
                const int jm = NFFT - j;
                float2 Wj = ds[SL2(j)];
                float2 Wm = ds[SL2(jm)];
                float Ex = 0.5f * (Wj.x + Wm.x), Ey = 0.5f * (Wj.y - Wm.y);
                float Dx = 0.5f * (Wj.x - Wm.x), Dy = 0.5f * (Wj.y + Wm.y);
                float Ox = Dy, Oy = -Dx;                         // O = -i*D
                float s_, c_;
                __sincosf(PI_F * (float)j / 8192.0f, &s_, &c_);
                float2 tO = cmul(make_float2(c_, -s_), make_float2(Ox, Oy));
                float2 uO = cmul(make_float2(c_,  s_), make_float2(Ox, -Oy));
                kc[j]  = make_float2((Ex + tO.x) * sc, ( Ey + tO.y) * sc);
                kc[jm] = make_float2((Ex - uO.x) * sc, (-Ey - uO.y) * sc);
            }
        }
    }
}

// ====== Kernel B: per (b,c): W=FFT(x even/odd) -> untangle*K*tangle -> IFFT -> y ======
__global__ __launch_bounds__(NT2)
void hyena_xconv8(const float* __restrict__ x, const float2* __restrict__ kw,
                  float* __restrict__ y)
{
    __shared__ alignas(16) float2 ds[NFFT];       // 64 KiB -> 2 blocks/CU
    const int bid = blockIdx.x, tid = threadIdx.x;
    const int c = bid >> 1, b = bid & 1;          // adjacent blocks share K row
    const int B_ = tid << 1;
    const float* xp = x + ((size_t)(b * CCH + c)) * LSEQ;
    float*       yp = y + ((size_t)(b * CCH + c)) * LSEQ;

    {   // forward pass0: w[e] = x[2e] + i*x[2e+1]; e >= 4096 zero.
        float2 a0,a1,a2,a3,a4,a5,a6,a7,b0,b1,b2,b3,b4,b5,b6,b7;
        float4 v;
        v = *(const float4*)&xp[(B_ << 1)];
        a0 = make_float2(v.x, v.y); b0 = make_float2(v.z, v.w);
        v = *(const float4*)&xp[(B_ << 1) + 2048];
        a1 = make_float2(v.x, v.y); b1 = make_float2(v.z, v.w);
        v = *(const float4*)&xp[(B_ << 1) + 4096];
        a2 = make_float2(v.x, v.y); b2 = make_float2(v.z, v.w);
        v = *(const float4*)&xp[(B_ << 1) + 6144];
        a3 = make_float2(v.x, v.y); b3 = make_float2(v.z, v.w);
        a4 = a5 = a6 = a7 = b4 = b5 = b6 = b7 = make_float2(0.f, 0.f);
        DFT8AB(-1)
        WR8SEQ
        __syncthreads();
    }
    P8MID(-1, 8,  WD8C,  WD8S)
    P8MID(-1, 64, WD64C, WD64S)
    {   // final radix-16 forward, in place.
        R16_LOAD_TWIDDLE(-1)
        DFT16M(-1, m)
        R16_STORE_LDS
    }
    __syncthreads();

    // Untangle X, multiply by K, tangle to V (pairs (j, N-j) owned per thread).
    {
        const float2* kc = kw + (size_t)c * KSTRIDE;
#pragma unroll
        for (int r = 0; r < 8; r++) {
            const int j = tid + (r << 9);
            if (j == 0) {
                float2 W0 = ds[SL2(0)];
                float X0 = W0.x + W0.y, XN = W0.x - W0.y;
                float2 K0 = kc[0], KN = kc[8192];
                float2 Z0 = make_float2(X0 * K0.x, X0 * K0.y);
                float2 ZN = make_float2(XN * KN.x, XN * KN.y);
                ds[SL2(0)] = make_float2(Z0.x + ZN.x - (Z0.y - ZN.y),
                                         Z0.y + ZN.y + (Z0.x - ZN.x));
                float2 W4 = ds[SL2(4096)];
                float2 Z4 = cmul(conjf2(W4), kc[4096]);
                ds[SL2(4096)] = make_float2(2.f * Z4.x, -2.f * Z4.y);
            } else {
                const int jm = NFFT - j;
                float2 Wj = ds[SL2(j)];
                float2 Wm = ds[SL2(jm)];
                float Ex = 0.5f * (Wj.x + Wm.x), Ey = 0.5f * (Wj.y - Wm.y);
                float Dx = 0.5f * (Wj.x - Wm.x), Dy = 0.5f * (Wj.y + Wm.y);
                float Ox = Dy, Oy = -Dx;
                float s_, c_;
                __sincosf(PI_F * (float)j / 8192.0f, &s_, &c_);
                float2 tO = cmul(make_float2(c_, -s_), make_float2(Ox, Oy));
                float2 Xj = make_float2(Ex + tO.x,  Ey + tO.y);
                float2 uO = cmul(make_float2(c_,  s_), make_float2(Ox, -Oy));
                float2 Xm = make_float2(Ex - uO.x, -Ey - uO.y);
                float2 Zj = cmul(Xj, kc[j]);
                float2 Zm = cmul(Xm, kc[jm]);
                // V[j] = (Zj + conj Zm) + i e^{i pi j/N} (Zj - conj Zm)
                float2 P = make_float2(Zj.x + Zm.x, Zj.y - Zm.y);
                float2 Q = make_float2(Zj.x - Zm.x, Zj.y + Zm.y);
                float2 Vj = make_float2(P.x - s_ * Q.x - c_ * Q.y,
                                        P.y - s_ * Q.y + c_ * Q.x);
                // V[jm]: i e^{i pi jm/N} = (-s_, -c_)
                float2 P2 = make_float2(Zm.x + Zj.x, Zm.y - Zj.y);
                float2 Q2 = make_float2(Zm.x - Zj.x, Zm.y + Zj.y);
                float2 Vm = make_float2(P2.x - s_ * Q2.x + c_ * Q2.y,
                                        P2.y - s_ * Q2.y - c_ * Q2.x);
                ds[SL2(j)]  = Vj;
                ds[SL2(jm)] = Vm;
            }
        }
    }
    __syncthreads();

    // Inverse FFT (unscaled; scaling folded into K).
    P8FIRST_LDS(1)
    P8MID(1, 8,  WD8C,  WD8S)
    P8MID(1, 64, WD64C, WD64S)
    {   // final inverse radix-16: v[n] for n < 4096 only -> y[2n], y[2n+1].
        R16_LOAD_TWIDDLE(1)
        DFT16M(1, m)
        *(float2*)&yp[(tid) << 1]          = m0;
        *(float2*)&yp[(tid +  512) << 1]   = m4;
        *(float2*)&yp[(tid + 1024) << 1]   = m8;
        *(float2*)&yp[(tid + 1536) << 1]   = m12;
        *(float2*)&yp[(tid + 2048) << 1]   = m1;
        *(float2*)&yp[(tid + 2560) << 1]   = m5;
        *(float2*)&yp[(tid + 3072) << 1]   = m9;
        *(float2*)&yp[(tid + 3584) << 1]   = m13;
    }
}

extern "C" void kernel_launch(void* const* d_in, const int* in_sizes, int n_in,
                              void* d_out, int out_size, void* d_ws, size_t ws_size,
                              hipStream_t stream) {
    const float* x    = (const float*)d_in[0];
    const float* k    = (const float*)d_in[1];
    const float* bias = (const float*)d_in[2];
    float* y          = (float*)d_out;
    float2* kw        = (float2*)d_ws;   // >= 2048*8208*8 B (~134 MB; verified available in R8/R9)

    hyena_kfft8 <<<dim3(CCH),     dim3(NT2), 0, stream>>>(k, bias, kw);
    hyena_xconv8<<<dim3(2 * CCH), dim3(NT2), 0, stream>>>(x, kw, y);
}